// Round 19
// baseline (191.160 us; speedup 1.0000x reference)
//
#include <hip/hip_runtime.h>
#include <hip/hip_bf16.h>

// R19 = R16 with barriers halved CLEANLY (R14 retest without the reg blowup):
// 4 K/V buffers (kt&3; 64KB) + Pt 16KB = 80KB -> still exactly 2 blocks/CU.
// One raw s_barrier per 2 tiles (16 total, was 32): vmcnt(0) -> barrier ->
// stage pair p+1 -> R13 per-tile body x2 (byte-identical body, regs ~64).
// 8-wave blocks (16 waves/CU), 2 rowtiles/wave, shared aK per kk, bV on the
// fly. exp2-native fixed-max softmax (scores bounded -> m=0, exact).
// bf16 MFMA flash attention, pre-swizzled K/V tile images in ws.
// B=4 H=16 S=2048 D=64, f32 in/out, multiplicative mask.

typedef __attribute__((ext_vector_type(4))) float  f32x4;
typedef __attribute__((ext_vector_type(8))) short  short8;
typedef __attribute__((ext_vector_type(4))) short  short4v;

constexpr int S = 2048, D = 64;
constexpr int NBH = 64;
constexpr int QBLK = 256, KT = 64;
constexpr int NQT = S / QBLK;      // 8
constexpr int NKT = S / KT;        // 32
constexpr int NP  = NKT / 2;       // 16 barrier pairs
constexpr float SCALE = 0.125f * 1.44269504088896340736f;  // (1/T)*log2(e)
constexpr size_t TILE_SH = (size_t)KT * D;                 // 4096 shorts (8KB) per tile
constexpr size_t IMG_SH  = (size_t)NBH * NKT * TILE_SH;
constexpr size_t WS_NEED = 2 * IMG_SH * sizeof(short);     // 33.55 MB

__device__ inline unsigned short bfb(float x) {
    union { __hip_bfloat16 h; unsigned short u; } cv;
    cv.h = __float2bfloat16(x);
    return cv.u;
}

__device__ inline float fexp2(float x) {   // native v_exp_f32 (exp2)
#if __has_builtin(__builtin_amdgcn_exp2f)
    return __builtin_amdgcn_exp2f(x);
#else
    return __expf(x * 0.6931471805599453f);
#endif
}

__device__ inline void gload16(const short* g, short* l) {
    auto gp = (const __attribute__((address_space(1))) int*)g;
    auto lp = (__attribute__((address_space(3))) int*)l;
    __builtin_amdgcn_global_load_lds(gp, lp, 16, 0, 0);
}

// ---- merged pre-pass (64-key tiles, 64-wide rows) — unchanged.
// blocks [0, NBH*NKT):        K -> swizzled bf16 tile image [key][d^8*(key&7)]
// blocks [NBH*NKT, 2*NBH*NKT): V -> transposed swizzled image [d][key^8*(d&7)]
__global__ __launch_bounds__(256)
void conv_kv(const float* __restrict__ K, const float* __restrict__ V,
             short* __restrict__ Kimg, short* __restrict__ Vimg) {
    const int t = threadIdx.x;
    const int nt = NBH * NKT;
    if (blockIdx.x < nt) {
        const float* src = K + (size_t)blockIdx.x * TILE_SH;
        short* dst = Kimg + (size_t)blockIdx.x * TILE_SH;
        const int row = t >> 2, c16 = (t & 3) * 16;
        const int swz = (row & 7) << 3;
        float4 f0 = *reinterpret_cast<const float4*>(src + row * D + c16 + 0);
        float4 f1 = *reinterpret_cast<const float4*>(src + row * D + c16 + 4);
        float4 f2 = *reinterpret_cast<const float4*>(src + row * D + c16 + 8);
        float4 f3 = *reinterpret_cast<const float4*>(src + row * D + c16 + 12);
        short8 a, b;
        a[0]=bfb(f0.x); a[1]=bfb(f0.y); a[2]=bfb(f0.z); a[3]=bfb(f0.w);
        a[4]=bfb(f1.x); a[5]=bfb(f1.y); a[6]=bfb(f1.z); a[7]=bfb(f1.w);
        b[0]=bfb(f2.x); b[1]=bfb(f2.y); b[2]=bfb(f2.z); b[3]=bfb(f2.w);
        b[4]=bfb(f3.x); b[5]=bfb(f3.y); b[6]=bfb(f3.z); b[7]=bfb(f3.w);
        *reinterpret_cast<short8*>(dst + row * 64 + (c16 ^ swz)) = a;
        *reinterpret_cast<short8*>(dst + row * 64 + ((c16 + 8) ^ swz)) = b;
    } else {
        __shared__ float tl[64][65];
        const int blk = blockIdx.x - nt;
        const float* src = V + (size_t)blk * TILE_SH;
        short* dst = Vimg + (size_t)blk * TILE_SH;
        const int row = t >> 2, c16 = (t & 3) * 16;
        {
            float4 f0 = *reinterpret_cast<const float4*>(src + row * D + c16 + 0);
            float4 f1 = *reinterpret_cast<const float4*>(src + row * D + c16 + 4);
            float4 f2 = *reinterpret_cast<const float4*>(src + row * D + c16 + 8);
            float4 f3 = *reinterpret_cast<const float4*>(src + row * D + c16 + 12);
            tl[row][c16+0]=f0.x;  tl[row][c16+1]=f0.y;  tl[row][c16+2]=f0.z;  tl[row][c16+3]=f0.w;
            tl[row][c16+4]=f1.x;  tl[row][c16+5]=f1.y;  tl[row][c16+6]=f1.z;  tl[row][c16+7]=f1.w;
            tl[row][c16+8]=f2.x;  tl[row][c16+9]=f2.y;  tl[row][c16+10]=f2.z; tl[row][c16+11]=f2.w;
            tl[row][c16+12]=f3.x; tl[row][c16+13]=f3.y; tl[row][c16+14]=f3.z; tl[row][c16+15]=f3.w;
        }
        __syncthreads();
        const int d = t >> 2, k16 = (t & 3) * 16;
        const int swz = (d & 7) << 3;
        float vv[16];
#pragma unroll
        for (int j = 0; j < 16; ++j) vv[j] = tl[k16 + j][d];
        short8 a, b;
#pragma unroll
        for (int j = 0; j < 8; ++j) { a[j] = bfb(vv[j]); b[j] = bfb(vv[j + 8]); }
        *reinterpret_cast<short8*>(dst + d * 64 + (k16 ^ swz)) = a;
        *reinterpret_cast<short8*>(dst + d * 64 + ((k16 + 8) ^ swz)) = b;
    }
}

// ---- main attention kernel: 8 waves x 32 q-rows (2 rowtiles) each
__global__ __launch_bounds__(512)
void attn_img(const float* __restrict__ Q, const float* __restrict__ M,
              const short* __restrict__ Kimg, const short* __restrict__ Vimg,
              float* __restrict__ O)
{
    __shared__ short Kb[4][4096];     // 4 x 8 KB quad buffer
    __shared__ short Vb[4][4096];     // 4 x 8 KB
    __shared__ short Pt[8][16][64];   // 16 KB: one rowtile per wave
    // total 80 KB -> exactly 2 blocks/CU

    const int tid  = threadIdx.x;
    const int w    = tid >> 6;        // 0..7
    const int lane = tid & 63;
    const int g    = lane >> 4;
    const int c    = lane & 15;
    const int swz8 = (c & 7) << 3;    // fragment-read swizzle (row%8 == c%8)

    const int bid = blockIdx.x;
    const int bh  = bid >> 3;         // consecutive bids share bh -> L2 reuse
    const int qt  = bid & 7;
    const int qw  = qt * QBLK + w * 32;

    const size_t bhS = (size_t)bh * S;
    const size_t bhT = (size_t)bh * NKT;

    // ---- Q fragments (B operand): bQ[rt][kk], row = qw+rt*16+c, k = d
    short8 bQ[2][2];
#pragma unroll
    for (int rt = 0; rt < 2; ++rt) {
        const float* qp = Q + (bhS + qw + rt * 16 + c) * D;
#pragma unroll
        for (int kk = 0; kk < 2; ++kk) {
            const float* q8 = qp + kk * 32 + g * 8;
            float4 a = *reinterpret_cast<const float4*>(q8);
            float4 b = *reinterpret_cast<const float4*>(q8 + 4);
            short8 r;
            r[0] = bfb(a.x * SCALE); r[1] = bfb(a.y * SCALE);
            r[2] = bfb(a.z * SCALE); r[3] = bfb(a.w * SCALE);
            r[4] = bfb(b.x * SCALE); r[5] = bfb(b.y * SCALE);
            r[6] = bfb(b.z * SCALE); r[7] = bfb(b.w * SCALE);
            bQ[rt][kk] = r;
        }
    }

    const float* mrow0 = M + (size_t)(qw + c) * S;
    const float* mrow1 = M + (size_t)(qw + 16 + c) * S;

    f32x4 acc[2][4] = {};             // [rt][d-ntile] (AGPRs)
    float lR[2] = {0.f, 0.f};         // per-lane partial denominator

    // stage: 512 threads x 16B = full 8KB tile in ONE pass per tensor
    auto stage = [&](int buf, int kt) {
        const short* ks = Kimg + (bhT + kt) * TILE_SH + tid * 8;
        const short* vs = Vimg + (bhT + kt) * TILE_SH + tid * 8;
        gload16(ks, &Kb[buf][tid * 8]);
        gload16(vs, &Vb[buf][tid * 8]);
    };

    // R13 per-tile compute body (byte-identical structure)
    auto tile = [&](int kt) {
        const short* Kt = Kb[kt & 3];
        const short* Vt = Vb[kt & 3];
        const int k0 = kt * KT;

        f32x4 s[2][4] = {};
#pragma unroll
        for (int kk = 0; kk < 2; ++kk) {
            short8 aK[4];
#pragma unroll
            for (int n = 0; n < 4; ++n)
                aK[n] = *reinterpret_cast<const short8*>(
                    &Kt[(n * 16 + c) * 64 + ((kk * 32 + g * 8) ^ swz8)]);
            __builtin_amdgcn_s_setprio(1);
#pragma unroll
            for (int n = 0; n < 4; ++n) {
                s[0][n] = __builtin_amdgcn_mfma_f32_16x16x32_bf16(
                    aK[n], bQ[0][kk], s[0][n], 0, 0, 0);
                s[1][n] = __builtin_amdgcn_mfma_f32_16x16x32_bf16(
                    aK[n], bQ[1][kk], s[1][n], 0, 0, 0);
            }
            __builtin_amdgcn_s_setprio(0);
        }

#pragma unroll
        for (int rt = 0; rt < 2; ++rt) {
            const float* mrow = rt ? mrow1 : mrow0;

            float lp = 0.f;
#pragma unroll
            for (int n = 0; n < 4; ++n) {
                float4 mk = *reinterpret_cast<const float4*>(mrow + k0 + n * 16 + g * 4);
                float e0 = fexp2(s[rt][n][0] * mk.x);
                float e1 = fexp2(s[rt][n][1] * mk.y);
                float e2 = fexp2(s[rt][n][2] * mk.z);
                float e3 = fexp2(s[rt][n][3] * mk.w);
                lp += (e0 + e1) + (e2 + e3);
                short4v pk;
                pk[0] = bfb(e0); pk[1] = bfb(e1); pk[2] = bfb(e2); pk[3] = bfb(e3);
                *reinterpret_cast<short4v*>(
                    &Pt[w][c][(n * 16 + g * 4) ^ swz8]) = pk;
            }
            lR[rt] += lp;

#pragma unroll
            for (int kk = 0; kk < 2; ++kk) {
                short8 aP = *reinterpret_cast<const short8*>(
                    &Pt[w][c][(kk * 32 + g * 8) ^ swz8]);
                __builtin_amdgcn_s_setprio(1);
#pragma unroll
                for (int n = 0; n < 4; ++n) {
                    short8 bV = *reinterpret_cast<const short8*>(
                        &Vt[(n * 16 + c) * 64 + ((kk * 32 + g * 8) ^ swz8)]);
                    acc[rt][n] = __builtin_amdgcn_mfma_f32_16x16x32_bf16(
                        aP, bV, acc[rt][n], 0, 0, 0);
                }
                __builtin_amdgcn_s_setprio(0);
            }
        }
    };

    // prologue: stage pair 0 (tiles 0,1)
    stage(0, 0);
    stage(1, 1);

    for (int p = 0; p < NP; ++p) {
        // masks of pair p-1 already auto-drained by their uses; the only
        // outstanding VMEM is this pair's 4 stage loads -> vmcnt(0) is cheap.
        asm volatile("s_waitcnt vmcnt(0)" ::: "memory");
        __builtin_amdgcn_s_barrier();          // ONE raw barrier per 2 tiles
        __builtin_amdgcn_sched_barrier(0);

        if (p + 1 < NP) {                      // stage pair p+1 (overwrites p-1's bufs: safe past barrier)
            stage((2 * p + 2) & 3, 2 * p + 2);
            stage((2 * p + 3) & 3, 2 * p + 3);
        }

        tile(2 * p);
        tile(2 * p + 1);
    }

    // ---- epilogue: single cross-lane reduce of denominator, normalize, store
#pragma unroll
    for (int rt = 0; rt < 2; ++rt) {
        float l = lR[rt];
        l += __shfl_xor(l, 16);
        l += __shfl_xor(l, 32);        // full denom for q-row (rt,c)
        const float linv = 1.0f / l;
        float ld[4];
        ld[0] = __shfl(linv, 4 * g + 0);
        ld[1] = __shfl(linv, 4 * g + 1);
        ld[2] = __shfl(linv, 4 * g + 2);
        ld[3] = __shfl(linv, 4 * g + 3);
#pragma unroll
        for (int r = 0; r < 4; ++r) {
            float* op = O + (bhS + qw + rt * 16 + 4 * g + r) * D + c;
#pragma unroll
            for (int n = 0; n < 4; ++n) op[n * 16] = acc[rt][n][r] * ld[r];
        }
    }
}

// ---- fallback (ws too small): known-correct f32 kernel
constexpr int FQT = 256, FKT = 64, FSUB = 16;
__global__ __launch_bounds__(FQT)
void attn_f32(const float* __restrict__ Q, const float* __restrict__ K,
              const float* __restrict__ V, const float* __restrict__ M,
              float* __restrict__ O)
{
    __shared__ float Kt[FKT][D];
    __shared__ float Vt[FKT][D];
    const int tid = threadIdx.x;
    const int bh = blockIdx.x / (S / FQT);
    const int qrow = (blockIdx.x % (S / FQT)) * FQT + tid;
    const float* qp = Q + ((size_t)bh * S + qrow) * D;
    const float* mp = M + (size_t)qrow * S;
    const float* kb = K + (size_t)bh * S * D;
    const float* vb = V + (size_t)bh * S * D;
    float qv[D];
#pragma unroll
    for (int d = 0; d < D; d += 4) {
        float4 t = *reinterpret_cast<const float4*>(qp + d);
        qv[d] = t.x * 0.125f; qv[d+1] = t.y * 0.125f; qv[d+2] = t.z * 0.125f; qv[d+3] = t.w * 0.125f;
    }
    float acc[D];
#pragma unroll
    for (int d = 0; d < D; ++d) acc[d] = 0.f;
    float mrun = -1e30f, lrun = 0.f;
    for (int k0 = 0; k0 < S; k0 += FKT) {
        __syncthreads();
        const float4* ks = reinterpret_cast<const float4*>(kb + (size_t)k0 * D);
        const float4* vs = reinterpret_cast<const float4*>(vb + (size_t)k0 * D);
        float4* kd = reinterpret_cast<float4*>(&Kt[0][0]);
        float4* vd = reinterpret_cast<float4*>(&Vt[0][0]);
#pragma unroll
        for (int i = 0; i < (FKT * D / 4) / FQT; ++i) {
            kd[tid + FQT * i] = ks[tid + FQT * i];
            vd[tid + FQT * i] = vs[tid + FQT * i];
        }
        __syncthreads();
        for (int j0 = 0; j0 < FKT; j0 += FSUB) {
            float mk[FSUB];
#pragma unroll
            for (int i = 0; i < FSUB; i += 4) {
                float4 t = *reinterpret_cast<const float4*>(mp + k0 + j0 + i);
                mk[i] = t.x; mk[i+1] = t.y; mk[i+2] = t.z; mk[i+3] = t.w;
            }
            float sx[FSUB];
#pragma unroll
            for (int j = 0; j < FSUB; ++j) sx[j] = 0.f;
#pragma unroll
            for (int d = 0; d < D; d += 4)
#pragma unroll
                for (int j = 0; j < FSUB; ++j) {
                    float4 kv = *reinterpret_cast<const float4*>(&Kt[j0 + j][d]);
                    sx[j] = fmaf(qv[d], kv.x, sx[j]);
                    sx[j] = fmaf(qv[d+1], kv.y, sx[j]);
                    sx[j] = fmaf(qv[d+2], kv.z, sx[j]);
                    sx[j] = fmaf(qv[d+3], kv.w, sx[j]);
                }
            float cmax = -1e30f;
#pragma unroll
            for (int j = 0; j < FSUB; ++j) { sx[j] *= mk[j]; cmax = fmaxf(cmax, sx[j]); }
            if (cmax > mrun) {
                float r = __expf(mrun - cmax);
                mrun = cmax; lrun *= r;
#pragma unroll
                for (int d = 0; d < D; ++d) acc[d] *= r;
            }
#pragma unroll
            for (int j = 0; j < FSUB; ++j) {
                float p = __expf(sx[j] - mrun);
                lrun += p;
#pragma unroll
                for (int d = 0; d < D; d += 4) {
                    float4 vv = *reinterpret_cast<const float4*>(&Vt[j0 + j][d]);
                    acc[d] = fmaf(p, vv.x, acc[d]);
                    acc[d+1] = fmaf(p, vv.y, acc[d+1]);
                    acc[d+2] = fmaf(p, vv.z, acc[d+2]);
                    acc[d+3] = fmaf(p, vv.w, acc[d+3]);
                }
            }
        }
    }
    const float invl = 1.0f / lrun;
    float* op = O + ((size_t)bh * S + qrow) * D;
#pragma unroll
    for (int d = 0; d < D; d += 4) {
        float4 t;
        t.x = acc[d] * invl; t.y = acc[d+1] * invl; t.z = acc[d+2] * invl; t.w = acc[d+3] * invl;
        *reinterpret_cast<float4*>(op + d) = t;
    }
}

extern "C" void kernel_launch(void* const* d_in, const int* in_sizes, int n_in,
                              void* d_out, int out_size, void* d_ws, size_t ws_size,
                              hipStream_t stream) {
    const float* q = (const float*)d_in[0];
    const float* k = (const float*)d_in[1];
    const float* v = (const float*)d_in[2];
    const float* m = (const float*)d_in[3];
    float* out = (float*)d_out;
    if (ws_size >= WS_NEED) {
        short* kimg = (short*)d_ws;
        short* vimg = kimg + IMG_SH;
        conv_kv<<<dim3(2 * NBH * NKT), dim3(256), 0, stream>>>(k, v, kimg, vimg);
        attn_img<<<dim3(NBH * NQT), dim3(512), 0, stream>>>(q, m, kimg, vimg, out);
    } else {
        attn_f32<<<dim3(NBH * (S / FQT)), dim3(256), 0, stream>>>(q, k, v, m, out);
    }
}

// Round 20
// 159.348 us; speedup vs baseline: 1.1996x; 1.1996x over previous
//
#include <hip/hip_runtime.h>
#include <hip/hip_bf16.h>

// R20 = R16 verbatim (best measured: 159.4us). R14/R17/R19 showed every
// added-state variant tips the (VGPR+AGPR<=128, LDS<=80KB) joint constraint
// to 1 block/CU; R15/R16 showed LDS-op count and barrier drain aren't
// binding. Locking in the best-known configuration.
// 8-wave blocks (16 waves/CU), 2 rowtiles/wave, K/V triple-buffer + counted
// vmcnt (never 0 mid-loop), shared aK per kk, bV on the fly.
// exp2-native fixed-max softmax (scores bounded -> m=0, exact).
// bf16 MFMA flash attention, pre-swizzled K/V tile images in ws.
// B=4 H=16 S=2048 D=64, f32 in/out, multiplicative mask.

typedef __attribute__((ext_vector_type(4))) float  f32x4;
typedef __attribute__((ext_vector_type(8))) short  short8;
typedef __attribute__((ext_vector_type(4))) short  short4v;

constexpr int S = 2048, D = 64;
constexpr int NBH = 64;
constexpr int QBLK = 256, KT = 64;
constexpr int NQT = S / QBLK;      // 8
constexpr int NKT = S / KT;        // 32
constexpr float SCALE = 0.125f * 1.44269504088896340736f;  // (1/T)*log2(e)
constexpr size_t TILE_SH = (size_t)KT * D;                 // 4096 shorts (8KB) per tile
constexpr size_t IMG_SH  = (size_t)NBH * NKT * TILE_SH;
constexpr size_t WS_NEED = 2 * IMG_SH * sizeof(short);     // 33.55 MB

__device__ inline unsigned short bfb(float x) {
    union { __hip_bfloat16 h; unsigned short u; } cv;
    cv.h = __float2bfloat16(x);
    return cv.u;
}

__device__ inline float fexp2(float x) {   // native v_exp_f32 (exp2)
#if __has_builtin(__builtin_amdgcn_exp2f)
    return __builtin_amdgcn_exp2f(x);
#else
    return __expf(x * 0.6931471805599453f);
#endif
}

__device__ inline void gload16(const short* g, short* l) {
    auto gp = (const __attribute__((address_space(1))) int*)g;
    auto lp = (__attribute__((address_space(3))) int*)l;
    __builtin_amdgcn_global_load_lds(gp, lp, 16, 0, 0);
}

// ---- merged pre-pass (64-key tiles, 64-wide rows).
// blocks [0, NBH*NKT):        K -> swizzled bf16 tile image [key][d^8*(key&7)]
// blocks [NBH*NKT, 2*NBH*NKT): V -> transposed swizzled image [d][key^8*(d&7)]
__global__ __launch_bounds__(256)
void conv_kv(const float* __restrict__ K, const float* __restrict__ V,
             short* __restrict__ Kimg, short* __restrict__ Vimg) {
    const int t = threadIdx.x;
    const int nt = NBH * NKT;
    if (blockIdx.x < nt) {
        const float* src = K + (size_t)blockIdx.x * TILE_SH;
        short* dst = Kimg + (size_t)blockIdx.x * TILE_SH;
        const int row = t >> 2, c16 = (t & 3) * 16;
        const int swz = (row & 7) << 3;
        float4 f0 = *reinterpret_cast<const float4*>(src + row * D + c16 + 0);
        float4 f1 = *reinterpret_cast<const float4*>(src + row * D + c16 + 4);
        float4 f2 = *reinterpret_cast<const float4*>(src + row * D + c16 + 8);
        float4 f3 = *reinterpret_cast<const float4*>(src + row * D + c16 + 12);
        short8 a, b;
        a[0]=bfb(f0.x); a[1]=bfb(f0.y); a[2]=bfb(f0.z); a[3]=bfb(f0.w);
        a[4]=bfb(f1.x); a[5]=bfb(f1.y); a[6]=bfb(f1.z); a[7]=bfb(f1.w);
        b[0]=bfb(f2.x); b[1]=bfb(f2.y); b[2]=bfb(f2.z); b[3]=bfb(f2.w);
        b[4]=bfb(f3.x); b[5]=bfb(f3.y); b[6]=bfb(f3.z); b[7]=bfb(f3.w);
        *reinterpret_cast<short8*>(dst + row * 64 + (c16 ^ swz)) = a;
        *reinterpret_cast<short8*>(dst + row * 64 + ((c16 + 8) ^ swz)) = b;
    } else {
        __shared__ float tl[64][65];
        const int blk = blockIdx.x - nt;
        const float* src = V + (size_t)blk * TILE_SH;
        short* dst = Vimg + (size_t)blk * TILE_SH;
        const int row = t >> 2, c16 = (t & 3) * 16;
        {
            float4 f0 = *reinterpret_cast<const float4*>(src + row * D + c16 + 0);
            float4 f1 = *reinterpret_cast<const float4*>(src + row * D + c16 + 4);
            float4 f2 = *reinterpret_cast<const float4*>(src + row * D + c16 + 8);
            float4 f3 = *reinterpret_cast<const float4*>(src + row * D + c16 + 12);
            tl[row][c16+0]=f0.x;  tl[row][c16+1]=f0.y;  tl[row][c16+2]=f0.z;  tl[row][c16+3]=f0.w;
            tl[row][c16+4]=f1.x;  tl[row][c16+5]=f1.y;  tl[row][c16+6]=f1.z;  tl[row][c16+7]=f1.w;
            tl[row][c16+8]=f2.x;  tl[row][c16+9]=f2.y;  tl[row][c16+10]=f2.z; tl[row][c16+11]=f2.w;
            tl[row][c16+12]=f3.x; tl[row][c16+13]=f3.y; tl[row][c16+14]=f3.z; tl[row][c16+15]=f3.w;
        }
        __syncthreads();
        const int d = t >> 2, k16 = (t & 3) * 16;
        const int swz = (d & 7) << 3;
        float vv[16];
#pragma unroll
        for (int j = 0; j < 16; ++j) vv[j] = tl[k16 + j][d];
        short8 a, b;
#pragma unroll
        for (int j = 0; j < 8; ++j) { a[j] = bfb(vv[j]); b[j] = bfb(vv[j + 8]); }
        *reinterpret_cast<short8*>(dst + d * 64 + (k16 ^ swz)) = a;
        *reinterpret_cast<short8*>(dst + d * 64 + ((k16 + 8) ^ swz)) = b;
    }
}

// ---- main attention kernel: 8 waves x 32 q-rows (2 rowtiles) each
__global__ __launch_bounds__(512)
void attn_img(const float* __restrict__ Q, const float* __restrict__ M,
              const short* __restrict__ Kimg, const short* __restrict__ Vimg,
              float* __restrict__ O)
{
    __shared__ short Kb[3][4096];     // 3 x 8 KB triple buffer
    __shared__ short Vb[3][4096];     // 3 x 8 KB
    __shared__ short Pt[8][16][64];   // 16 KB: one rowtile per wave
    // total 64 KB -> 2 blocks/CU

    const int tid  = threadIdx.x;
    const int w    = tid >> 6;        // 0..7
    const int lane = tid & 63;
    const int g    = lane >> 4;
    const int c    = lane & 15;
    const int swz8 = (c & 7) << 3;    // fragment-read swizzle (row%8 == c%8)

    const int bid = blockIdx.x;
    const int bh  = bid >> 3;         // consecutive bids share bh -> L2 reuse
    const int qt  = bid & 7;
    const int qw  = qt * QBLK + w * 32;

    const size_t bhS = (size_t)bh * S;
    const size_t bhT = (size_t)bh * NKT;

    // ---- Q fragments (B operand): bQ[rt][kk], row = qw+rt*16+c, k = d
    short8 bQ[2][2];
#pragma unroll
    for (int rt = 0; rt < 2; ++rt) {
        const float* qp = Q + (bhS + qw + rt * 16 + c) * D;
#pragma unroll
        for (int kk = 0; kk < 2; ++kk) {
            const float* q8 = qp + kk * 32 + g * 8;
            float4 a = *reinterpret_cast<const float4*>(q8);
            float4 b = *reinterpret_cast<const float4*>(q8 + 4);
            short8 r;
            r[0] = bfb(a.x * SCALE); r[1] = bfb(a.y * SCALE);
            r[2] = bfb(a.z * SCALE); r[3] = bfb(a.w * SCALE);
            r[4] = bfb(b.x * SCALE); r[5] = bfb(b.y * SCALE);
            r[6] = bfb(b.z * SCALE); r[7] = bfb(b.w * SCALE);
            bQ[rt][kk] = r;
        }
    }

    const float* mrow0 = M + (size_t)(qw + c) * S;
    const float* mrow1 = M + (size_t)(qw + 16 + c) * S;

    f32x4 acc[2][4] = {};             // [rt][d-ntile] (AGPRs)
    float lR[2] = {0.f, 0.f};         // per-lane partial denominator

    // stage: 512 threads x 16B = full 8KB tile in ONE pass per tensor
    auto stage = [&](int buf, int kt) {
        const short* ks = Kimg + (bhT + kt) * TILE_SH + tid * 8;
        const short* vs = Vimg + (bhT + kt) * TILE_SH + tid * 8;
        gload16(ks, &Kb[buf][tid * 8]);
        gload16(vs, &Vb[buf][tid * 8]);
    };

    stage(0, 0);
    stage(1, 1);

    for (int kt = 0; kt < NKT; ++kt) {
        // T4: wait for stage(kt) only; stage(kt+1)/(kt+2) stay in flight.
        if (kt == NKT - 1) {
            asm volatile("s_waitcnt vmcnt(0)" ::: "memory");
        } else {
            asm volatile("s_waitcnt vmcnt(2)" ::: "memory");
        }
        __builtin_amdgcn_s_barrier();          // raw barrier, no drain
        __builtin_amdgcn_sched_barrier(0);     // pin: nothing moves across

        if (kt + 2 < NKT) stage((kt + 2) % 3, kt + 2);

        const short* Kt = Kb[kt % 3];
        const short* Vt = Vb[kt % 3];
        const int k0 = kt * KT;

        // ---- QK^T for both rowtiles, aK shared per kk (8 indep chains)
        f32x4 s[2][4] = {};
#pragma unroll
        for (int kk = 0; kk < 2; ++kk) {
            short8 aK[4];
#pragma unroll
            for (int n = 0; n < 4; ++n)
                aK[n] = *reinterpret_cast<const short8*>(
                    &Kt[(n * 16 + c) * 64 + ((kk * 32 + g * 8) ^ swz8)]);
            __builtin_amdgcn_s_setprio(1);
#pragma unroll
            for (int n = 0; n < 4; ++n) {
                s[0][n] = __builtin_amdgcn_mfma_f32_16x16x32_bf16(
                    aK[n], bQ[0][kk], s[0][n], 0, 0, 0);
                s[1][n] = __builtin_amdgcn_mfma_f32_16x16x32_bf16(
                    aK[n], bQ[1][kk], s[1][n], 0, 0, 0);
            }
            __builtin_amdgcn_s_setprio(0);
        }

        // ---- per rt: mask*exp2 (fixed max 0, exact) -> P -> PV
#pragma unroll
        for (int rt = 0; rt < 2; ++rt) {
            const float* mrow = rt ? mrow1 : mrow0;

            float lp = 0.f;
#pragma unroll
            for (int n = 0; n < 4; ++n) {
                float4 mk = *reinterpret_cast<const float4*>(mrow + k0 + n * 16 + g * 4);
                float e0 = fexp2(s[rt][n][0] * mk.x);
                float e1 = fexp2(s[rt][n][1] * mk.y);
                float e2 = fexp2(s[rt][n][2] * mk.z);
                float e3 = fexp2(s[rt][n][3] * mk.w);
                lp += (e0 + e1) + (e2 + e3);
                short4v pk;
                pk[0] = bfb(e0); pk[1] = bfb(e1); pk[2] = bfb(e2); pk[3] = bfb(e3);
                *reinterpret_cast<short4v*>(
                    &Pt[w][c][(n * 16 + g * 4) ^ swz8]) = pk;
            }
            lR[rt] += lp;

            // ---- PV: A = P (this rt), B = V^T image (read per-MFMA)
#pragma unroll
            for (int kk = 0; kk < 2; ++kk) {
                short8 aP = *reinterpret_cast<const short8*>(
                    &Pt[w][c][(kk * 32 + g * 8) ^ swz8]);
                __builtin_amdgcn_s_setprio(1);
#pragma unroll
                for (int n = 0; n < 4; ++n) {
                    short8 bV = *reinterpret_cast<const short8*>(
                        &Vt[(n * 16 + c) * 64 + ((kk * 32 + g * 8) ^ swz8)]);
                    acc[rt][n] = __builtin_amdgcn_mfma_f32_16x16x32_bf16(
                        aP, bV, acc[rt][n], 0, 0, 0);
                }
                __builtin_amdgcn_s_setprio(0);
            }
        }
    }

    // ---- epilogue: single cross-lane reduce of denominator, normalize, store
#pragma unroll
    for (int rt = 0; rt < 2; ++rt) {
        float l = lR[rt];
        l += __shfl_xor(l, 16);
        l += __shfl_xor(l, 32);        // full denom for q-row (rt,c)
        const float linv = 1.0f / l;
        float ld[4];
        ld[0] = __shfl(linv, 4 * g + 0);
        ld[1] = __shfl(linv, 4 * g + 1);
        ld[2] = __shfl(linv, 4 * g + 2);
        ld[3] = __shfl(linv, 4 * g + 3);
#pragma unroll
        for (int r = 0; r < 4; ++r) {
            float* op = O + (bhS + qw + rt * 16 + 4 * g + r) * D + c;
#pragma unroll
            for (int n = 0; n < 4; ++n) op[n * 16] = acc[rt][n][r] * ld[r];
        }
    }
}

// ---- fallback (ws too small): known-correct f32 kernel
constexpr int FQT = 256, FKT = 64, FSUB = 16;
__global__ __launch_bounds__(FQT)
void attn_f32(const float* __restrict__ Q, const float* __restrict__ K,
              const float* __restrict__ V, const float* __restrict__ M,
              float* __restrict__ O)
{
    __shared__ float Kt[FKT][D];
    __shared__ float Vt[FKT][D];
    const int tid = threadIdx.x;
    const int bh = blockIdx.x / (S / FQT);
    const int qrow = (blockIdx.x % (S / FQT)) * FQT + tid;
    const float* qp = Q + ((size_t)bh * S + qrow) * D;
    const float* mp = M + (size_t)qrow * S;
    const float* kb = K + (size_t)bh * S * D;
    const float* vb = V + (size_t)bh * S * D;
    float qv[D];
#pragma unroll
    for (int d = 0; d < D; d += 4) {
        float4 t = *reinterpret_cast<const float4*>(qp + d);
        qv[d] = t.x * 0.125f; qv[d+1] = t.y * 0.125f; qv[d+2] = t.z * 0.125f; qv[d+3] = t.w * 0.125f;
    }
    float acc[D];
#pragma unroll
    for (int d = 0; d < D; ++d) acc[d] = 0.f;
    float mrun = -1e30f, lrun = 0.f;
    for (int k0 = 0; k0 < S; k0 += FKT) {
        __syncthreads();
        const float4* ks = reinterpret_cast<const float4*>(kb + (size_t)k0 * D);
        const float4* vs = reinterpret_cast<const float4*>(vb + (size_t)k0 * D);
        float4* kd = reinterpret_cast<float4*>(&Kt[0][0]);
        float4* vd = reinterpret_cast<float4*>(&Vt[0][0]);
#pragma unroll
        for (int i = 0; i < (FKT * D / 4) / FQT; ++i) {
            kd[tid + FQT * i] = ks[tid + FQT * i];
            vd[tid + FQT * i] = vs[tid + FQT * i];
        }
        __syncthreads();
        for (int j0 = 0; j0 < FKT; j0 += FSUB) {
            float mk[FSUB];
#pragma unroll
            for (int i = 0; i < FSUB; i += 4) {
                float4 t = *reinterpret_cast<const float4*>(mp + k0 + j0 + i);
                mk[i] = t.x; mk[i+1] = t.y; mk[i+2] = t.z; mk[i+3] = t.w;
            }
            float sx[FSUB];
#pragma unroll
            for (int j = 0; j < FSUB; ++j) sx[j] = 0.f;
#pragma unroll
            for (int d = 0; d < D; d += 4)
#pragma unroll
                for (int j = 0; j < FSUB; ++j) {
                    float4 kv = *reinterpret_cast<const float4*>(&Kt[j0 + j][d]);
                    sx[j] = fmaf(qv[d], kv.x, sx[j]);
                    sx[j] = fmaf(qv[d+1], kv.y, sx[j]);
                    sx[j] = fmaf(qv[d+2], kv.z, sx[j]);
                    sx[j] = fmaf(qv[d+3], kv.w, sx[j]);
                }
            float cmax = -1e30f;
#pragma unroll
            for (int j = 0; j < FSUB; ++j) { sx[j] *= mk[j]; cmax = fmaxf(cmax, sx[j]); }
            if (cmax > mrun) {
                float r = __expf(mrun - cmax);
                mrun = cmax; lrun *= r;
#pragma unroll
                for (int d = 0; d < D; ++d) acc[d] *= r;
            }
#pragma unroll
            for (int j = 0; j < FSUB; ++j) {
                float p = __expf(sx[j] - mrun);
                lrun += p;
#pragma unroll
                for (int d = 0; d < D; d += 4) {
                    float4 vv = *reinterpret_cast<const float4*>(&Vt[j0 + j][d]);
                    acc[d] = fmaf(p, vv.x, acc[d]);
                    acc[d+1] = fmaf(p, vv.y, acc[d+1]);
                    acc[d+2] = fmaf(p, vv.z, acc[d+2]);
                    acc[d+3] = fmaf(p, vv.w, acc[d+3]);
                }
            }
        }
    }
    const float invl = 1.0f / lrun;
    float* op = O + ((size_t)bh * S + qrow) * D;
#pragma unroll
    for (int d = 0; d < D; d += 4) {
        float4 t;
        t.x = acc[d] * invl; t.y = acc[d+1] * invl; t.z = acc[d+2] * invl; t.w = acc[d+3] * invl;
        *reinterpret_cast<float4*>(op + d) = t;
    }
}

extern "C" void kernel_launch(void* const* d_in, const int* in_sizes, int n_in,
                              void* d_out, int out_size, void* d_ws, size_t ws_size,
                              hipStream_t stream) {
    const float* q = (const float*)d_in[0];
    const float* k = (const float*)d_in[1];
    const float* v = (const float*)d_in[2];
    const float* m = (const float*)d_in[3];
    float* out = (float*)d_out;
    if (ws_size >= WS_NEED) {
        short* kimg = (short*)d_ws;
        short* vimg = kimg + IMG_SH;
        conv_kv<<<dim3(2 * NBH * NKT), dim3(256), 0, stream>>>(k, v, kimg, vimg);
        attn_img<<<dim3(NBH * NQT), dim3(512), 0, stream>>>(q, m, kimg, vimg, out);
    } else {
        attn_f32<<<dim3(NBH * (S / FQT)), dim3(256), 0, stream>>>(q, k, v, m, out);
    }
}